// Round 5
// baseline (1444.181 us; speedup 1.0000x reference)
//
#include <hip/hip_runtime.h>

constexpr int NPER = 52;     // nodes per graph
constexpr int HID  = 128;
constexpr int INCH = 21;
constexpr int NLAY = 4;
constexpr int LATD = 64;
constexpr int NGRAPH = 256;
constexpr int TPB  = 1024;   // 16 waves: 8 producer + 8 consumer
constexpr int TSTR = 424;    // elems per k-block of a frag-tile (848 B)
constexpr int TILE = 16 * TSTR;

typedef short short8 __attribute__((ext_vector_type(8)));
typedef float f32x4  __attribute__((ext_vector_type(4)));

// ---------------- d_ws bf16 weight layout (all transposed to [n][k]) ----------------
constexpr int W1T_OFF = 0;                         // [L][256 n][128 k]
constexpr int W1T_SZ  = NLAY * 256 * HID;
constexpr int W2T_OFF = W1T_OFF + W1T_SZ;          // [L][128 n][128 k]
constexpr int W2T_SZ  = NLAY * HID * HID;
constexpr int C1T_OFF = W2T_OFF + W2T_SZ;          // [L][128 n][128 k]
constexpr int C1T_SZ  = NLAY * HID * HID;
constexpr int N1T_OFF = C1T_OFF + C1T_SZ;          // [L][128 n][256 k]
constexpr int N1T_SZ  = NLAY * HID * 2 * HID;
constexpr int N2T_OFF = N1T_OFF + N1T_SZ;          // [L][128 n][128 k]
constexpr int N2T_SZ  = NLAY * HID * HID;
constexpr int WS_ELEMS = N2T_OFF + N2T_SZ;         // 458,752 bf16 = 917,504 B

__device__ __forceinline__ unsigned cvt_pk_bf16(float a, float b) {
    unsigned r;
    asm("v_cvt_pk_bf16_f32 %0, %1, %2" : "=v"(r) : "v"(a), "v"(b));
    return r;
}
__device__ __forceinline__ unsigned short f2bf(float f) {
    return (unsigned short)cvt_pk_bf16(f, f);
}
__device__ __forceinline__ float bf2f(unsigned short h) {
    return __uint_as_float(((unsigned)h) << 16);
}
__device__ __forceinline__ float blo(unsigned u) { return __uint_as_float(u << 16); }
__device__ __forceinline__ float bhi(unsigned u) { return __uint_as_float(u & 0xffff0000u); }
__device__ __forceinline__ float fast_rcp(float x) {
    float r;
    asm("v_rcp_f32 %0, %1" : "=v"(r) : "v"(x));
    return r;
}
__device__ __forceinline__ float silu_f(float v) {
    return v * fast_rcp(1.0f + __expf(-v));
}
__device__ __forceinline__ f32x4 mfma16(short8 a, short8 b, f32x4 c) {
    return __builtin_amdgcn_mfma_f32_16x16x32_bf16(a, b, c, 0, 0, 0);
}
// frag-tile element index: [k-block e>>3][row][e&7]
__device__ __forceinline__ int tidx(int row, int e) {
    return (e >> 3) * TSTR + row * 8 + (e & 7);
}

// ---------------- weight conversion: fp32 -> bf16 transposed, into d_ws ----------------
__global__ void conv_w(const float* __restrict__ ew1, const float* __restrict__ ew2,
                       const float* __restrict__ cw1, const float* __restrict__ nw1,
                       const float* __restrict__ nw2, unsigned short* __restrict__ ws)
{
    int idx = blockIdx.x * 256 + threadIdx.x;
    if (idx >= WS_ELEMS) return;
    float v;
    if (idx < W2T_OFF) {
        int t = idx - W1T_OFF;
        int L = t / (256 * HID), rem = t % (256 * HID);
        int n = rem / HID, k = rem % HID;
        v = (n < HID) ? ew1[(size_t)L * 257 * HID + k * HID + n]
                      : ew1[(size_t)L * 257 * HID + (HID + k) * HID + (n - HID)];
    } else if (idx < C1T_OFF) {
        int t = idx - W2T_OFF;
        int L = t / (HID * HID), rem = t % (HID * HID);
        int n = rem / HID, k = rem % HID;
        v = ew2[(size_t)L * HID * HID + k * HID + n];
    } else if (idx < N1T_OFF) {
        int t = idx - C1T_OFF;
        int L = t / (HID * HID), rem = t % (HID * HID);
        int n = rem / HID, k = rem % HID;
        v = cw1[(size_t)L * HID * HID + k * HID + n];
    } else if (idx < N2T_OFF) {
        int t = idx - N1T_OFF;
        int L = t / (HID * 2 * HID), rem = t % (HID * 2 * HID);
        int n = rem / (2 * HID), k = rem % (2 * HID);
        v = nw1[(size_t)L * 2 * HID * HID + k * HID + n];
    } else {
        int t = idx - N2T_OFF;
        int L = t / (HID * HID), rem = t % (HID * HID);
        int n = rem / HID, k = rem % HID;
        v = nw2[(size_t)L * HID * HID + k * HID + n];
    }
    ws[idx] = f2bf(v);
}

// ---------------- LDS ----------------
// frag-tiles: mb[2 slot][2 rr], ef[2 rr], h, ag (8 tiles, TSTR-padded)
// linear bf16: A_l, B_l [52][128]
// floats: wr 128, rad [2][2][64], tpartp [2 slot][2 rr][4 np][64], aggf [2 mp][2 rr][128],
//         coord 156, cacc 156
constexpr int LDS_SHORTS = 8 * TILE + 2 * NPER * HID;
constexpr int LDS_FLOATS = 128 + 256 + 1024 + 512 + 156 + 156;
constexpr size_t SHMEM_BYTES = (size_t)LDS_SHORTS * 2 + (size_t)LDS_FLOATS * 4; // 144,096

extern "C" __global__ void __launch_bounds__(TPB)
egnn_mfma(const float* __restrict__ x, const float* __restrict__ pos,
          const float* __restrict__ emb_in_w, const float* __restrict__ emb_in_b,
          const float* __restrict__ edge_w1,
          const float* __restrict__ edge_b1, const float* __restrict__ edge_b2,
          const float* __restrict__ node_b1, const float* __restrict__ node_b2,
          const float* __restrict__ coord_b1, const float* __restrict__ coord_w2,
          const float* __restrict__ emb_out_w, const float* __restrict__ emb_out_b,
          const float* __restrict__ mean_w, const float* __restrict__ mean_b,
          const float* __restrict__ logvar_w, const float* __restrict__ logvar_b,
          const unsigned short* __restrict__ ws, float* __restrict__ out)
{
    extern __shared__ __align__(16) char smem[];
    unsigned short* mb   = (unsigned short*)smem;        // 4 frag-tiles: [slot][rr]
    unsigned short* ef_t = mb + 4 * TILE;                // 2 frag-tiles: [rr]
    unsigned short* h_t  = ef_t + 2 * TILE;
    unsigned short* ag_t = h_t + TILE;
    unsigned short* A_l  = ag_t + TILE;                  // [52][128] linear
    unsigned short* B_l  = A_l + NPER * HID;             // [52][128] linear
    float* wr_s   = (float*)(B_l + NPER * HID);          // [128]
    float* rad_s  = wr_s + 128;                          // [2 slot][2 rr][64]
    float* tpartp = rad_s + 256;                         // [2 slot][2 rr][4 np][64]
    float* aggf   = tpartp + 1024;                       // [2 mp][2 rr][128]
    float* coord_s = aggf + 512;                         // [156]
    float* cacc_s  = coord_s + 156;                      // [156]

    const int g    = blockIdx.x;
    const int tid  = threadIdx.x;
    const int lane = tid & 63;
    const int wv   = tid >> 6;            // 0..15
    const int l15  = lane & 15;
    const int kb   = lane >> 4;           // 0..3
    const bool cons = (wv >= 8);

    // all-wave map (AB-GEMM, node MLP): 4 mp x 4 np
    const int mp4 = wv >> 2, np4 = wv & 3;
    const int rowA4 = mp4 * 16 + l15;
    const int crow4 = mp4 * 16 + kb * 4;
    const int n0_4 = 32 * np4 + l15, n1_4 = n0_4 + 16;

    // consumer map: 2 mpc x 4 npc
    const int mpc = (wv >> 2) & 1;        // valid for wv>=8
    const int npc = wv & 3;
    const int rw0 = mpc * 32 + l15, rw1 = rw0 + 16;
    const int rowc = mpc * 32 + kb * 4;
    const int nc0 = npc * 32 + l15, nc1 = nc0 + 16;
    const int eb0 = (nc0 >> 3) * TSTR + (nc0 & 7);
    const int eb1x = (nc1 >> 3) * TSTR + (nc1 & 7);

    // producer map
    const int pw = wv;                    // 0..7
    const int rrp = pw >> 2;              // 0..3 -> rr0, 4..7 -> rr1
    const int cb = 13 * pw - 52 * rrp;    // local row base
    const int half = lane >> 5;
    const int col4 = (lane & 31) * 4;
    const int wb = (col4 >> 3) * TSTR + (col4 & 7);

    // ---------- init ----------
    {
        float* xs = (float*)mb;
        for (int p = tid; p < NPER * INCH; p += TPB) xs[p] = x[(size_t)g * NPER * INCH + p];
        for (int p = tid; p < NPER * 3; p += TPB)    coord_s[p] = pos[(size_t)g * NPER * 3 + p];
    }
    __syncthreads();

    // ---------- embedding_in ----------
    for (int p = tid; p < NPER * HID; p += TPB) {
        int c = p >> 7, j = p & 127;
        float s = emb_in_b[j];
        #pragma unroll 7
        for (int k = 0; k < INCH; ++k) s += ((float*)mb)[c * INCH + k] * emb_in_w[k * HID + j];
        h_t[tidx(c, j)] = f2bf(s);
    }
    __syncthreads();

    // ---------- layers ----------
    for (int L = 0; L < NLAY; ++L) {
        const unsigned short* w1t = ws + W1T_OFF + (size_t)L * 256 * HID;
        const unsigned short* w2t = ws + W2T_OFF + (size_t)L * HID * HID;
        const unsigned short* c1t = ws + C1T_OFF + (size_t)L * HID * HID;
        const unsigned short* n1t = ws + N1T_OFF + (size_t)L * HID * 2 * HID;
        const unsigned short* n2t = ws + N2T_OFF + (size_t)L * HID * HID;

        // ---- AB phase (all waves): [A|B] = h @ ew1 (+eb1 on A half); + wr, rad(0..3) ----
        {
            f32x4 acc[4];
            #pragma unroll
            for (int q = 0; q < 4; ++q) acc[q] = (f32x4){0.f, 0.f, 0.f, 0.f};
            #pragma unroll
            for (int s = 0; s < 4; ++s) {
                short8 af = *(const short8*)(h_t + (4 * s + kb) * TSTR + rowA4 * 8);
                #pragma unroll
                for (int q = 0; q < 4; ++q) {
                    int n = l15 + 16 * (4 * np4 + q);
                    short8 bf = *(const short8*)(w1t + (size_t)n * HID + 32 * s + 8 * kb);
                    acc[q] = mfma16(af, bf, acc[q]);
                }
            }
            #pragma unroll
            for (int q = 0; q < 4; ++q) {
                int n = l15 + 16 * (4 * np4 + q);
                float eb1 = (n < HID) ? edge_b1[L * HID + n] : 0.f;
                #pragma unroll
                for (int reg = 0; reg < 4; ++reg) {
                    int c = crow4 + reg;
                    if (c < NPER) {
                        float v = acc[q][reg] + eb1;
                        if (n < HID) A_l[c * HID + n] = f2bf(v);
                        else         B_l[c * HID + (n - HID)] = f2bf(v);
                    }
                }
            }
            if (tid < HID) wr_s[tid] = edge_w1[(size_t)L * 257 * HID + 256 * HID + tid];
            if (wv < 4 && lane < NPER) {            // rad for r = 0..3 (pairs 0,1)
                int r = wv;
                float dx = coord_s[r * 3 + 0] - coord_s[lane * 3 + 0];
                float dy = coord_s[r * 3 + 1] - coord_s[lane * 3 + 1];
                float dz = coord_s[r * 3 + 2] - coord_s[lane * 3 + 2];
                rad_s[(r >> 1) * 128 + (r & 1) * 64 + lane] = dx * dx + dy * dy + dz * dz;
            }
        }
        __syncthreads();

        // consumer-held weights (loaded in ph0)
        short8 wE0[4], wE1[4], wC0[4], wC1[4];
        float eb2v[2], cb1v[2], cw2v[2];

        // ---- ph0: prod -> m(0); cons -> load weights ----
        if (cons) {
            #pragma unroll
            for (int s = 0; s < 4; ++s) {
                wE0[s] = *(const short8*)(w2t + (size_t)nc0 * HID + 32 * s + 8 * kb);
                wE1[s] = *(const short8*)(w2t + (size_t)nc1 * HID + 32 * s + 8 * kb);
                wC0[s] = *(const short8*)(c1t + (size_t)nc0 * HID + 32 * s + 8 * kb);
                wC1[s] = *(const short8*)(c1t + (size_t)nc1 * HID + 32 * s + 8 * kb);
            }
            eb2v[0] = edge_b2[L * HID + nc0];  eb2v[1] = edge_b2[L * HID + nc1];
            cb1v[0] = coord_b1[L * HID + nc0]; cb1v[1] = coord_b1[L * HID + nc1];
            cw2v[0] = coord_w2[L * HID + nc0]; cw2v[1] = coord_w2[L * HID + nc1];
        } else {
            // m-step for pair 0
            const int pt = 0;
            const int r = 2 * pt + rrp;
            unsigned short* mt_ = mb + ((pt & 1) * 2 + rrp) * TILE;
            const float* radp = rad_s + (pt & 1) * 128 + rrp * 64;
            uint2 a2 = *(const uint2*)(A_l + r * HID + col4);
            float A0 = blo(a2.x), A1 = bhi(a2.x), A2 = blo(a2.y), A3 = bhi(a2.y);
            float4 w4 = *(const float4*)(wr_s + col4);
            #pragma unroll
            for (int i = 0; i < 7; ++i) {
                int lr = 2 * i + half;
                if (lr < 13) {
                    int c = cb + lr;
                    float rad = radp[c];
                    uint2 b2 = *(const uint2*)(B_l + c * HID + col4);
                    float v0 = A0 + blo(b2.x) + rad * w4.x;
                    float v1 = A1 + bhi(b2.x) + rad * w4.y;
                    float v2 = A2 + blo(b2.y) + rad * w4.z;
                    float v3 = A3 + bhi(b2.y) + rad * w4.w;
                    uint2 o;
                    o.x = cvt_pk_bf16(silu_f(v0), silu_f(v1));
                    o.y = cvt_pk_bf16(silu_f(v2), silu_f(v3));
                    *(uint2*)(mt_ + wb + c * 8) = o;
                }
            }
        }
        __syncthreads();

        // ---- pipelined edge loop: 2 barriers per pair ----
        for (int p = 0; p < 26; ++p) {
            // ===== ph1: cons GEMM1(p) ; prod m(p+1) =====
            if (cons) {
                #pragma unroll
                for (int rr = 0; rr < 2; ++rr) {
                    const unsigned short* mt_ = mb + ((p & 1) * 2 + rr) * TILE;
                    f32x4 a00 = (f32x4){0.f,0.f,0.f,0.f}, a01 = a00, a10 = a00, a11 = a00;
                    #pragma unroll
                    for (int s = 0; s < 4; ++s) {
                        short8 f0 = *(const short8*)(mt_ + (4 * s + kb) * TSTR + rw0 * 8);
                        short8 f1 = *(const short8*)(mt_ + (4 * s + kb) * TSTR + rw1 * 8);
                        a00 = mfma16(f0, wE0[s], a00);
                        a01 = mfma16(f0, wE1[s], a01);
                        a10 = mfma16(f1, wE0[s], a10);
                        a11 = mfma16(f1, wE1[s], a11);
                    }
                    const int r = 2 * p + rr;
                    unsigned short* et = ef_t + rr * TILE;
                    float as0 = 0.f, as1 = 0.f;
                    #pragma unroll
                    for (int mt2 = 0; mt2 < 2; ++mt2) {
                        f32x4 va = mt2 ? a10 : a00;
                        f32x4 vb = mt2 ? a11 : a01;
                        #pragma unroll
                        for (int reg = 0; reg < 4; ++reg) {
                            int c = rowc + mt2 * 16 + reg;
                            float v0 = silu_f(va[reg] + eb2v[0]);
                            float v1 = silu_f(vb[reg] + eb2v[1]);
                            if (c < NPER) {
                                et[eb0 + c * 8] = f2bf(v0);
                                et[eb1x + c * 8] = f2bf(v1);
                                if (c != r) { as0 += v0; as1 += v1; }
                            }
                        }
                    }
                    as0 += __shfl_xor(as0, 16); as0 += __shfl_xor(as0, 32);
                    as1 += __shfl_xor(as1, 16); as1 += __shfl_xor(as1, 32);
                    if (kb == 0) {
                        aggf[(mpc * 2 + rr) * HID + nc0] = as0;
                        aggf[(mpc * 2 + rr) * HID + nc1] = as1;
                    }
                }
            } else if (p + 1 < 26) {
                const int pt = p + 1;
                const int r = 2 * pt + rrp;
                unsigned short* mt_ = mb + ((pt & 1) * 2 + rrp) * TILE;
                const float* radp = rad_s + (pt & 1) * 128 + rrp * 64;
                uint2 a2 = *(const uint2*)(A_l + r * HID + col4);
                float A0 = blo(a2.x), A1 = bhi(a2.x), A2 = blo(a2.y), A3 = bhi(a2.y);
                float4 w4 = *(const float4*)(wr_s + col4);
                #pragma unroll
                for (int i = 0; i < 7; ++i) {
                    int lr = 2 * i + half;
                    if (lr < 13) {
                        int c = cb + lr;
                        float rad = radp[c];
                        uint2 b2 = *(const uint2*)(B_l + c * HID + col4);
                        float v0 = A0 + blo(b2.x) + rad * w4.x;
                        float v1 = A1 + bhi(b2.x) + rad * w4.y;
                        float v2 = A2 + blo(b2.y) + rad * w4.z;
                        float v3 = A3 + bhi(b2.y) + rad * w4.w;
                        uint2 o;
                        o.x = cvt_pk_bf16(silu_f(v0), silu_f(v1));
                        o.y = cvt_pk_bf16(silu_f(v2), silu_f(v3));
                        *(uint2*)(mt_ + wb + c * 8) = o;
                    }
                }
            }
            __syncthreads();

            // ===== ph2: cons GEMM2(p) ; prod glue =====
            if (cons) {
                #pragma unroll
                for (int rr = 0; rr < 2; ++rr) {
                    const unsigned short* et = ef_t + rr * TILE;
                    f32x4 a00 = (f32x4){0.f,0.f,0.f,0.f}, a01 = a00, a10 = a00, a11 = a00;
                    #pragma unroll
                    for (int s = 0; s < 4; ++s) {
                        short8 f0 = *(const short8*)(et + (4 * s + kb) * TSTR + rw0 * 8);
                        short8 f1 = *(const short8*)(et + (4 * s + kb) * TSTR + rw1 * 8);
                        a00 = mfma16(f0, wC0[s], a00);
                        a01 = mfma16(f0, wC1[s], a01);
                        a10 = mfma16(f1, wC0[s], a10);
                        a11 = mfma16(f1, wC1[s], a11);
                    }
                    float* tpb = tpartp + ((p & 1) * 2 + rr) * 256 + npc * 64;
                    #pragma unroll
                    for (int mt2 = 0; mt2 < 2; ++mt2) {
                        f32x4 va = mt2 ? a10 : a00;
                        f32x4 vb = mt2 ? a11 : a01;
                        #pragma unroll
                        for (int reg = 0; reg < 4; ++reg) {
                            float t = silu_f(va[reg] + cb1v[0]) * cw2v[0]
                                    + silu_f(vb[reg] + cb1v[1]) * cw2v[1];
                            t += __shfl_xor(t, 1); t += __shfl_xor(t, 2);
                            t += __shfl_xor(t, 4); t += __shfl_xor(t, 8);
                            if (l15 == 0) tpb[rowc + mt2 * 16 + reg] = t;
                        }
                    }
                }
            } else {
                if (wv < 2) {                       // coord_agg(p-1)
                    if (p > 0) {
                        const int rr = wv, r = 2 * (p - 1) + rr;
                        const float* tb = tpartp + (((p - 1) & 1) * 2 + rr) * 256;
                        float dx = 0.f, dy = 0.f, dz = 0.f;
                        if (lane < NPER) {
                            float tc = tb[lane] + tb[64 + lane] + tb[128 + lane] + tb[192 + lane];
                            dx = (coord_s[r * 3 + 0] - coord_s[lane * 3 + 0]) * tc;
                            dy = (coord_s[r * 3 + 1] - coord_s[lane * 3 + 1]) * tc;
                            dz = (coord_s[r * 3 + 2] - coord_s[lane * 3 + 2]) * tc;
                        }
                        #pragma unroll
                        for (int m = 1; m < 64; m <<= 1) {
                            dx += __shfl_xor(dx, m); dy += __shfl_xor(dy, m); dz += __shfl_xor(dz, m);
                        }
                        if (lane == 0) {
                            cacc_s[r * 3 + 0] = dx; cacc_s[r * 3 + 1] = dy; cacc_s[r * 3 + 2] = dz;
                        }
                    }
                } else if (wv < 4) {                // rad(p+2)
                    if (p < 24 && lane < NPER) {
                        const int rr = wv - 2, rn = 2 * (p + 2) + rr;
                        float dx = coord_s[rn * 3 + 0] - coord_s[lane * 3 + 0];
                        float dy = coord_s[rn * 3 + 1] - coord_s[lane * 3 + 1];
                        float dz = coord_s[rn * 3 + 2] - coord_s[lane * 3 + 2];
                        rad_s[(p & 1) * 128 + rr * 64 + lane] = dx * dx + dy * dy + dz * dz;
                    }
                } else if (wv < 6) {                // aggf -> ag_t rows 2p, 2p+1
                    const int rr = wv - 4, r = 2 * p + rr;
                    #pragma unroll
                    for (int hh = 0; hh < 2; ++hh) {
                        int col = lane + hh * 64;
                        float s = aggf[rr * HID + col] + aggf[(2 + rr) * HID + col];
                        ag_t[(col >> 3) * TSTR + r * 8 + (col & 7)] = f2bf(s);
                    }
                }
            }
            __syncthreads();
        }

        // ---- drain: coord_agg(25) ----
        if (wv < 2) {
            const int rr = wv, r = 50 + rr;
            const float* tb = tpartp + (1 * 2 + rr) * 256;
            float dx = 0.f, dy = 0.f, dz = 0.f;
            if (lane < NPER) {
                float tc = tb[lane] + tb[64 + lane] + tb[128 + lane] + tb[192 + lane];
                dx = (coord_s[r * 3 + 0] - coord_s[lane * 3 + 0]) * tc;
                dy = (coord_s[r * 3 + 1] - coord_s[lane * 3 + 1]) * tc;
                dz = (coord_s[r * 3 + 2] - coord_s[lane * 3 + 2]) * tc;
            }
            #pragma unroll
            for (int m = 1; m < 64; m <<= 1) {
                dx += __shfl_xor(dx, m); dy += __shfl_xor(dy, m); dz += __shfl_xor(dz, m);
            }
            if (lane == 0) {
                cacc_s[r * 3 + 0] = dx; cacc_s[r * 3 + 1] = dy; cacc_s[r * 3 + 2] = dz;
            }
        }
        __syncthreads();

        // ---- coord update + node MLP part 1 (all waves): z -> mb tile 0 ----
        if (tid < NPER * 3) coord_s[tid] += cacc_s[tid] * (1.0f / 51.0f);
        {
            float nb1v[2];
            nb1v[0] = node_b1[L * HID + n0_4]; nb1v[1] = node_b1[L * HID + n1_4];
            f32x4 z0 = (f32x4){0.f,0.f,0.f,0.f}, z1 = z0;
            #pragma unroll
            for (int s = 0; s < 4; ++s) {
                short8 af = *(const short8*)(h_t + (4 * s + kb) * TSTR + rowA4 * 8);
                z0 = mfma16(af, *(const short8*)(n1t + (size_t)n0_4 * 2 * HID + 32 * s + 8 * kb), z0);
                z1 = mfma16(af, *(const short8*)(n1t + (size_t)n1_4 * 2 * HID + 32 * s + 8 * kb), z1);
            }
            #pragma unroll
            for (int s = 0; s < 4; ++s) {
                short8 af = *(const short8*)(ag_t + (4 * s + kb) * TSTR + rowA4 * 8);
                z0 = mfma16(af, *(const short8*)(n1t + (size_t)n0_4 * 2 * HID + HID + 32 * s + 8 * kb), z0);
                z1 = mfma16(af, *(const short8*)(n1t + (size_t)n1_4 * 2 * HID + HID + 32 * s + 8 * kb), z1);
            }
            __syncthreads();   // mb slot0 free (all GEMM1 reads done prior layer-loop)
            #pragma unroll
            for (int reg = 0; reg < 4; ++reg) {
                int c = crow4 + reg;
                if (c < NPER) {
                    mb[tidx(c, n0_4)] = f2bf(silu_f(z0[reg] + nb1v[0]));
                    mb[tidx(c, n1_4)] = f2bf(silu_f(z1[reg] + nb1v[1]));
                }
            }
        }
        __syncthreads();

        // ---- node MLP part 2: h += z @ nw2 + nb2 ----
        {
            float nb2v[2];
            nb2v[0] = node_b2[L * HID + n0_4]; nb2v[1] = node_b2[L * HID + n1_4];
            f32x4 d0 = (f32x4){0.f,0.f,0.f,0.f}, d1 = d0;
            #pragma unroll
            for (int s = 0; s < 4; ++s) {
                short8 af = *(const short8*)(mb + (4 * s + kb) * TSTR + rowA4 * 8);
                d0 = mfma16(af, *(const short8*)(n2t + (size_t)n0_4 * HID + 32 * s + 8 * kb), d0);
                d1 = mfma16(af, *(const short8*)(n2t + (size_t)n1_4 * HID + 32 * s + 8 * kb), d1);
            }
            #pragma unroll
            for (int reg = 0; reg < 4; ++reg) {
                int c = crow4 + reg;
                if (c < NPER) {
                    int i0 = tidx(c, n0_4), i1 = tidx(c, n1_4);
                    h_t[i0] = f2bf(bf2f(h_t[i0]) + d0[reg] + nb2v[0]);
                    h_t[i1] = f2bf(bf2f(h_t[i1]) + d1[reg] + nb2v[1]);
                }
            }
        }
        __syncthreads();
    }

    // ---------- head ----------
    float* gm = aggf;            // [128]
    float* eg = aggf + HID;      // [128]
    if (tid < HID) {
        float s = 0.f;
        for (int c = 0; c < NPER; ++c) s += bf2f(h_t[tidx(c, tid)]);
        gm[tid] = s * (1.0f / 52.0f);
    }
    __syncthreads();
    if (tid < HID) {
        float s = emb_out_b[tid];
        #pragma unroll 4
        for (int k = 0; k < HID; ++k) s += gm[k] * emb_out_w[k * HID + tid];
        eg[tid] = s;
    }
    __syncthreads();
    if (tid < 2 * LATD) {
        const int  l   = tid & (LATD - 1);
        const bool ism = tid < LATD;
        const float* W = ism ? mean_w : logvar_w;
        float s = ism ? mean_b[l] : logvar_b[l];
        #pragma unroll 4
        for (int k = 0; k < HID; ++k) s += eg[k] * W[k * LATD + l];
        out[(ism ? 0 : NGRAPH * LATD) + g * LATD + l] = s;
    }
}

extern "C" void kernel_launch(void* const* d_in, const int* in_sizes, int n_in,
                              void* d_out, int out_size, void* d_ws, size_t ws_size,
                              hipStream_t stream) {
    const float* x         = (const float*)d_in[0];
    const float* pos       = (const float*)d_in[1];
    // d_in[2..4] edge_row/edge_col/batch: block-diagonal FC structure is known.
    const float* emb_in_w  = (const float*)d_in[5];
    const float* emb_in_b  = (const float*)d_in[6];
    const float* edge_w1   = (const float*)d_in[7];
    const float* edge_b1   = (const float*)d_in[8];
    const float* edge_w2   = (const float*)d_in[9];
    const float* edge_b2   = (const float*)d_in[10];
    const float* node_w1   = (const float*)d_in[11];
    const float* node_b1   = (const float*)d_in[12];
    const float* node_w2   = (const float*)d_in[13];
    const float* node_b2   = (const float*)d_in[14];
    const float* coord_w1  = (const float*)d_in[15];
    const float* coord_b1  = (const float*)d_in[16];
    const float* coord_w2  = (const float*)d_in[17];
    const float* emb_out_w = (const float*)d_in[18];
    const float* emb_out_b = (const float*)d_in[19];
    const float* mean_w    = (const float*)d_in[20];
    const float* mean_b    = (const float*)d_in[21];
    const float* logvar_w  = (const float*)d_in[22];
    const float* logvar_b  = (const float*)d_in[23];

    unsigned short* ws = (unsigned short*)d_ws;   // needs 917,504 B

    conv_w<<<(WS_ELEMS + 255) / 256, 256, 0, stream>>>(edge_w1, edge_w2, coord_w1,
                                                       node_w1, node_w2, ws);

    (void)hipFuncSetAttribute(reinterpret_cast<const void*>(egnn_mfma),
                              hipFuncAttributeMaxDynamicSharedMemorySize,
                              (int)SHMEM_BYTES);

    hipLaunchKernelGGL(egnn_mfma, dim3(NGRAPH), dim3(TPB), SHMEM_BYTES, stream,
                       x, pos, emb_in_w, emb_in_b, edge_w1,
                       edge_b1, edge_b2, node_b1, node_b2,
                       coord_b1, coord_w2, emb_out_w, emb_out_b,
                       mean_w, mean_b, logvar_w, logvar_b,
                       ws, (float*)d_out);
}

// Round 6
// 806.182 us; speedup vs baseline: 1.7914x; 1.7914x over previous
//
#include <hip/hip_runtime.h>

constexpr int NPER = 52;     // nodes per graph
constexpr int HID  = 128;
constexpr int INCH = 21;
constexpr int NLAY = 4;
constexpr int LATD = 64;
constexpr int NGRAPH = 256;
constexpr int TPB  = 1024;   // 16 waves
constexpr int TSTR = 424;    // elems per k-block (848 B: 16B-aligned, bank-friendly)
constexpr int TILE = 16 * TSTR;   // 6784 elems per [52..64]x128 bf16 tile

typedef short short8 __attribute__((ext_vector_type(8)));
typedef float f32x4  __attribute__((ext_vector_type(4)));

// ---------------- d_ws bf16 weight layout (all transposed to [n][k]) ----------------
constexpr int W1T_OFF = 0;                         // [L][256 n][128 k]
constexpr int W1T_SZ  = NLAY * 256 * HID;
constexpr int W2T_OFF = W1T_OFF + W1T_SZ;          // [L][128 n][128 k]
constexpr int W2T_SZ  = NLAY * HID * HID;
constexpr int C1T_OFF = W2T_OFF + W2T_SZ;          // [L][128 n][128 k]
constexpr int C1T_SZ  = NLAY * HID * HID;
constexpr int N1T_OFF = C1T_OFF + C1T_SZ;          // [L][128 n][256 k]
constexpr int N1T_SZ  = NLAY * HID * 2 * HID;
constexpr int N2T_OFF = N1T_OFF + N1T_SZ;          // [L][128 n][128 k]
constexpr int N2T_SZ  = NLAY * HID * HID;
constexpr int WS_ELEMS = N2T_OFF + N2T_SZ;         // 458,752 bf16 = 917,504 B

__device__ __forceinline__ unsigned cvt_pk_bf16(float a, float b) {
    unsigned r;
    asm("v_cvt_pk_bf16_f32 %0, %1, %2" : "=v"(r) : "v"(a), "v"(b));
    return r;
}
__device__ __forceinline__ unsigned short f2bf(float f) {
    return (unsigned short)cvt_pk_bf16(f, f);
}
__device__ __forceinline__ float bf2f(unsigned short h) {
    return __uint_as_float(((unsigned)h) << 16);
}
__device__ __forceinline__ float fast_rcp(float x) {
    float r;
    asm("v_rcp_f32 %0, %1" : "=v"(r) : "v"(x));
    return r;
}
__device__ __forceinline__ float silu_f(float v) {
    return v * fast_rcp(1.0f + __expf(-v));
}
__device__ __forceinline__ f32x4 mfma16(short8 a, short8 b, f32x4 c) {
    return __builtin_amdgcn_mfma_f32_16x16x32_bf16(a, b, c, 0, 0, 0);
}

// fragment-native tile element index: [k-block e>>3][row][e&7]
__device__ __forceinline__ int tidx(int row, int e) {
    return (e >> 3) * TSTR + row * 8 + (e & 7);
}

// ---------------- weight conversion: fp32 -> bf16 transposed, into d_ws ----------------
__global__ void conv_w(const float* __restrict__ ew1, const float* __restrict__ ew2,
                       const float* __restrict__ cw1, const float* __restrict__ nw1,
                       const float* __restrict__ nw2, unsigned short* __restrict__ ws)
{
    int idx = blockIdx.x * 256 + threadIdx.x;
    if (idx >= WS_ELEMS) return;
    float v;
    if (idx < W2T_OFF) {
        int t = idx - W1T_OFF;
        int L = t / (256 * HID), rem = t % (256 * HID);
        int n = rem / HID, k = rem % HID;
        v = (n < HID) ? ew1[(size_t)L * 257 * HID + k * HID + n]
                      : ew1[(size_t)L * 257 * HID + (HID + k) * HID + (n - HID)];
    } else if (idx < C1T_OFF) {
        int t = idx - W2T_OFF;
        int L = t / (HID * HID), rem = t % (HID * HID);
        int n = rem / HID, k = rem % HID;
        v = ew2[(size_t)L * HID * HID + k * HID + n];
    } else if (idx < N1T_OFF) {
        int t = idx - C1T_OFF;
        int L = t / (HID * HID), rem = t % (HID * HID);
        int n = rem / HID, k = rem % HID;
        v = cw1[(size_t)L * HID * HID + k * HID + n];
    } else if (idx < N2T_OFF) {
        int t = idx - N1T_OFF;
        int L = t / (HID * 2 * HID), rem = t % (HID * 2 * HID);
        int n = rem / (2 * HID), k = rem % (2 * HID);
        v = nw1[(size_t)L * 2 * HID * HID + k * HID + n];
    } else {
        int t = idx - N2T_OFF;
        int L = t / (HID * HID), rem = t % (HID * HID);
        int n = rem / HID, k = rem % HID;
        v = nw2[(size_t)L * HID * HID + k * HID + n];
    }
    ws[idx] = f2bf(v);
}

// ---------------- LDS ----------------
// bf16 tiles (frag-native): m0, m1, ef0, ef1, h, ag, A, B
// floats: aggp[2][4][128], coord[156], cacc[156], rad[2][64], tpart[2][4][64], wr[128]
constexpr int LDS_FLOATS = 1024 + 156 + 156 + 128 + 512 + 128;   // 2104
constexpr size_t SHMEM_BYTES = (size_t)8 * TILE * 2 + LDS_FLOATS * 4;  // 116,960 B

__device__ __forceinline__ void coord_agg(int r, int rr, const float* tpart,
                                          const float* coord_s, float* cacc_s, int lane)
{
    float dx = 0.f, dy = 0.f, dz = 0.f;
    if (lane < NPER) {
        const float* tb = tpart + rr * 256;
        float tc = tb[lane] + tb[64 + lane] + tb[128 + lane] + tb[192 + lane];
        dx = (coord_s[r * 3 + 0] - coord_s[lane * 3 + 0]) * tc;
        dy = (coord_s[r * 3 + 1] - coord_s[lane * 3 + 1]) * tc;
        dz = (coord_s[r * 3 + 2] - coord_s[lane * 3 + 2]) * tc;
    }
    #pragma unroll
    for (int m = 1; m < 64; m <<= 1) {
        dx += __shfl_xor(dx, m); dy += __shfl_xor(dy, m); dz += __shfl_xor(dz, m);
    }
    if (lane == 0) {
        cacc_s[r * 3 + 0] = dx; cacc_s[r * 3 + 1] = dy; cacc_s[r * 3 + 2] = dz;
    }
}

// LDS is the occupancy limiter (1 block/CU = 4 waves/SIMD) -> budget 128 VGPRs/wave
// so the r-loop B-fragments (wE/wC, 64 VGPRs) actually live in registers (round-5
// post-mortem: default target chose 64 VGPRs and spilled them to scratch -> 356 MB
// FETCH_SIZE and a 1.8x regression).
extern "C" __global__ void __launch_bounds__(TPB, 4)
egnn_mfma(const float* __restrict__ x, const float* __restrict__ pos,
          const float* __restrict__ emb_in_w, const float* __restrict__ emb_in_b,
          const float* __restrict__ edge_w1,
          const float* __restrict__ edge_b1, const float* __restrict__ edge_b2,
          const float* __restrict__ node_b1, const float* __restrict__ node_b2,
          const float* __restrict__ coord_b1, const float* __restrict__ coord_w2,
          const float* __restrict__ emb_out_w, const float* __restrict__ emb_out_b,
          const float* __restrict__ mean_w, const float* __restrict__ mean_b,
          const float* __restrict__ logvar_w, const float* __restrict__ logvar_b,
          const unsigned short* __restrict__ ws, float* __restrict__ out)
{
    extern __shared__ __align__(16) char smem[];
    unsigned short* m0_t = (unsigned short*)smem;
    unsigned short* m1_t = m0_t + TILE;
    unsigned short* e0_t = m1_t + TILE;
    unsigned short* e1_t = e0_t + TILE;
    unsigned short* h_t  = e1_t + TILE;
    unsigned short* ag_t = h_t  + TILE;
    unsigned short* A_t  = ag_t + TILE;
    unsigned short* B_t  = A_t  + TILE;
    float* aggp    = (float*)(B_t + TILE);   // [2 rr][4 mp][128]
    float* coord_s = aggp + 1024;            // [52*3]
    float* cacc_s  = coord_s + 156;          // [52*3]
    float* rad_s   = cacc_s + 156;           // [2 rr][64]
    float* tpart   = rad_s + 128;            // [2 rr][4 np][64]
    float* wr_s    = tpart + 512;            // [128]

    const int g    = blockIdx.x;
    const int tid  = threadIdx.x;
    const int lane = tid & 63;
    const int wv   = tid >> 6;        // 0..15
    const int mp   = wv >> 2;         // 0..3 : M-tile (rows 16mp..16mp+15)
    const int np   = wv & 3;          // 0..3 : n-tile pair {2np, 2np+1}
    const int l15  = lane & 15;
    const int kb   = lane >> 4;       // 0..3
    const int rowA = mp * 16 + l15;
    const int crow0 = mp * 16 + kb * 4;
    const int n0   = 32 * np + l15;
    const int n1   = n0 + 16;
    const int jp   = 2 * lane;                       // m-step column pair
    const int pb   = (jp >> 3) * TSTR + (jp & 7);    // pair base (add c*8)
    const int fo   = kb * TSTR + rowA * 8;           // A-frag base (add s*4*TSTR)

    // ---------- init: stage x (f32 scratch in m0_t), pos ----------
    {
        float* xs = (float*)m0_t;
        for (int p = tid; p < NPER * INCH; p += TPB) xs[p] = x[(size_t)g * NPER * INCH + p];
        for (int p = tid; p < NPER * 3; p += TPB)    coord_s[p] = pos[(size_t)g * NPER * 3 + p];
    }
    __syncthreads();

    // ---------- embedding_in: h = x @ Wemb + b ----------
    for (int p = tid; p < NPER * HID; p += TPB) {
        int c = p >> 7, j = p & 127;
        float s = emb_in_b[j];
        #pragma unroll 7
        for (int k = 0; k < INCH; ++k) s += ((float*)m0_t)[c * INCH + k] * emb_in_w[k * HID + j];
        h_t[tidx(c, j)] = f2bf(s);
    }
    __syncthreads();

    // ---------- layers ----------
    for (int L = 0; L < NLAY; ++L) {
        const unsigned short* w1t = ws + W1T_OFF + (size_t)L * 256 * HID;
        const unsigned short* w2t = ws + W2T_OFF + (size_t)L * HID * HID;
        const unsigned short* c1t = ws + C1T_OFF + (size_t)L * HID * HID;
        const unsigned short* n1t = ws + N1T_OFF + (size_t)L * HID * 2 * HID;
        const unsigned short* n2t = ws + N2T_OFF + (size_t)L * HID * HID;

        // r-loop weights -> registers (shared by both rr chains)
        short8 wE[8], wC[8];
        #pragma unroll
        for (int s = 0; s < 4; ++s) {
            wE[s]     = *(const short8*)(w2t + (size_t)n0 * HID + 32 * s + 8 * kb);
            wE[4 + s] = *(const short8*)(w2t + (size_t)n1 * HID + 32 * s + 8 * kb);
            wC[s]     = *(const short8*)(c1t + (size_t)n0 * HID + 32 * s + 8 * kb);
            wC[4 + s] = *(const short8*)(c1t + (size_t)n1 * HID + 32 * s + 8 * kb);
        }
        float eb2v[2], cb1v[2], cw2v[2];
        eb2v[0] = edge_b2[L * HID + n0];  eb2v[1] = edge_b2[L * HID + n1];
        cb1v[0] = coord_b1[L * HID + n0]; cb1v[1] = coord_b1[L * HID + n1];
        cw2v[0] = coord_w2[L * HID + n0]; cw2v[1] = coord_w2[L * HID + n1];
        if (tid < HID) wr_s[tid] = edge_w1[(size_t)L * 257 * HID + 256 * HID + tid];

        // ---- AB-GEMM: [A|B] = h @ ew1[0:256] (+eb1 on A half) ----
        {
            f32x4 acc[4];
            #pragma unroll
            for (int q = 0; q < 4; ++q) acc[q] = (f32x4){0.f, 0.f, 0.f, 0.f};
            #pragma unroll
            for (int s = 0; s < 4; ++s) {
                short8 af = *(const short8*)(h_t + fo + s * 4 * TSTR);
                #pragma unroll
                for (int q = 0; q < 4; ++q) {
                    int n = l15 + 16 * (4 * np + q);
                    short8 bf = *(const short8*)(w1t + (size_t)n * HID + 32 * s + 8 * kb);
                    acc[q] = mfma16(af, bf, acc[q]);
                }
            }
            #pragma unroll
            for (int q = 0; q < 4; ++q) {
                int n = l15 + 16 * (4 * np + q);
                float eb1 = (n < HID) ? edge_b1[L * HID + n] : 0.f;
                #pragma unroll
                for (int reg = 0; reg < 4; ++reg) {
                    int c = crow0 + reg;
                    if (c < NPER) {
                        float v = acc[q][reg] + eb1;
                        if (n < HID) A_t[tidx(c, n)] = f2bf(v);
                        else         B_t[tidx(c, n - HID)] = f2bf(v);
                    }
                }
            }
        }
        // radial for group 0 (r=0,1)
        if (tid < NPER) {
            float dx = coord_s[0] - coord_s[tid * 3 + 0];
            float dy = coord_s[1] - coord_s[tid * 3 + 1];
            float dz = coord_s[2] - coord_s[tid * 3 + 2];
            rad_s[tid] = dx * dx + dy * dy + dz * dz;
        } else if (tid >= 64 && tid < 64 + NPER) {
            int c = tid - 64;
            float dx = coord_s[3] - coord_s[c * 3 + 0];
            float dy = coord_s[4] - coord_s[c * 3 + 1];
            float dz = coord_s[5] - coord_s[c * 3 + 2];
            rad_s[64 + c] = dx * dx + dy * dy + dz * dz;
        }
        __syncthreads();

        const float wrl = wr_s[jp], wrh = wr_s[jp + 1];

        // ---- edge loop: r-pairs, 3 barriers per pair ----
        for (int gp = 0; gp < 26; ++gp) {
            const int r0 = 2 * gp, r1 = r0 + 1;

            // region1: wave0 does coord-agg(prev pair); others compute m -> m0/m1
            {
                unsigned pa0 = *(const unsigned*)(A_t + pb + r0 * 8);
                unsigned pa1 = *(const unsigned*)(A_t + pb + r1 * 8);
                float A0l = bf2f((unsigned short)(pa0 & 0xffff)), A0h = bf2f((unsigned short)(pa0 >> 16));
                float A1l = bf2f((unsigned short)(pa1 & 0xffff)), A1h = bf2f((unsigned short)(pa1 >> 16));
                for (int j = wv; j < 2 * NPER; j += 16) {
                    int rr = (j >= NPER);
                    int c  = rr ? j - NPER : j;
                    float Al = rr ? A1l : A0l, Ah = rr ? A1h : A0h;
                    float rad = rad_s[rr * 64 + c];
                    unsigned bp = *(const unsigned*)(B_t + pb + c * 8);
                    float v0 = Al + bf2f((unsigned short)(bp & 0xffff)) + rad * wrl;
                    float v1 = Ah + bf2f((unsigned short)(bp >> 16))    + rad * wrh;
                    unsigned mv = cvt_pk_bf16(silu_f(v0), silu_f(v1));
                    *(unsigned*)((rr ? m1_t : m0_t) + pb + c * 8) = mv;
                }
            }
            __syncthreads();                            // bar A

            // region2: GEMM1 both rr (4 indep chains) + coord-agg of prev pair
            {
                f32x4 e00 = (f32x4){0.f,0.f,0.f,0.f}, e01 = e00, e10 = e00, e11 = e00;
                #pragma unroll
                for (int s = 0; s < 4; ++s) {
                    short8 af0 = *(const short8*)(m0_t + fo + s * 4 * TSTR);
                    short8 af1 = *(const short8*)(m1_t + fo + s * 4 * TSTR);
                    e00 = mfma16(af0, wE[s], e00); e01 = mfma16(af0, wE[4 + s], e01);
                    e10 = mfma16(af1, wE[s], e10); e11 = mfma16(af1, wE[4 + s], e11);
                }
                #pragma unroll
                for (int rr = 0; rr < 2; ++rr) {
                    f32x4 ea = rr ? e10 : e00, eb = rr ? e11 : e01;
                    unsigned short* et = rr ? e1_t : e0_t;
                    const int r = rr ? r1 : r0;
                    float a0 = 0.f, a1 = 0.f;
                    #pragma unroll
                    for (int reg = 0; reg < 4; ++reg) {
                        int c = crow0 + reg;
                        float v0 = silu_f(ea[reg] + eb2v[0]);
                        float v1 = silu_f(eb[reg] + eb2v[1]);
                        if (c < NPER) {
                            et[tidx(c, n0)] = f2bf(v0);
                            et[tidx(c, n1)] = f2bf(v1);
                            if (c != r) { a0 += v0; a1 += v1; }
                        }
                    }
                    a0 += __shfl_xor(a0, 16); a0 += __shfl_xor(a0, 32);
                    a1 += __shfl_xor(a1, 16); a1 += __shfl_xor(a1, 32);
                    if (kb == 0) {
                        float* ar = aggp + (rr * 4 + mp) * HID;
                        ar[n0] = a0; ar[n1] = a1;
                    }
                }
                if (wv < 2 && gp > 0) coord_agg(2 * gp - 2 + wv, wv, tpart, coord_s, cacc_s, lane);
            }
            __syncthreads();                            // bar C

            // region3: GEMM2 both rr -> tpart ; agg finalize ; radial for next pair
            {
                f32x4 y00 = (f32x4){0.f,0.f,0.f,0.f}, y01 = y00, y10 = y00, y11 = y00;
                #pragma unroll
                for (int s = 0; s < 4; ++s) {
                    short8 af0 = *(const short8*)(e0_t + fo + s * 4 * TSTR);
                    short8 af1 = *(const short8*)(e1_t + fo + s * 4 * TSTR);
                    y00 = mfma16(af0, wC[s], y00); y01 = mfma16(af0, wC[4 + s], y01);
                    y10 = mfma16(af1, wC[s], y10); y11 = mfma16(af1, wC[4 + s], y11);
                }
                #pragma unroll
                for (int rr = 0; rr < 2; ++rr) {
                    f32x4 ya = rr ? y10 : y00, yb = rr ? y11 : y01;
                    float* tp = tpart + (rr * 4 + np) * 64;
                    #pragma unroll
                    for (int reg = 0; reg < 4; ++reg) {
                        float v = silu_f(ya[reg] + cb1v[0]) * cw2v[0]
                                + silu_f(yb[reg] + cb1v[1]) * cw2v[1];
                        v += __shfl_xor(v, 1); v += __shfl_xor(v, 2);
                        v += __shfl_xor(v, 4); v += __shfl_xor(v, 8);
                        if (l15 == 0) tp[crow0 + reg] = v;
                    }
                }
            }
            if (tid < 256) {           // finalize agg rows r0, r1
                int rr = tid >> 7, t = tid & 127;
                const float* ap = aggp + rr * 512;
                float a = ap[t] + ap[128 + t] + ap[256 + t] + ap[384 + t];
                ag_t[tidx(2 * gp + rr, t)] = f2bf(a);
            } else if (tid < 384 && gp + 1 < 26) {     // radial for next pair
                int t = tid - 256, rr = t >> 6, c = t & 63;
                if (c < NPER) {
                    int r = 2 * (gp + 1) + rr;
                    float dx = coord_s[r * 3 + 0] - coord_s[c * 3 + 0];
                    float dy = coord_s[r * 3 + 1] - coord_s[c * 3 + 1];
                    float dz = coord_s[r * 3 + 2] - coord_s[c * 3 + 2];
                    rad_s[rr * 64 + c] = dx * dx + dy * dy + dz * dz;
                }
            }
            __syncthreads();                            // bar D
        }

        // post-loop: coord-agg(50,51) + node MLP part 1 (z -> m0_t)
        if (wv < 2) coord_agg(50 + wv, wv, tpart, coord_s, cacc_s, lane);
        {
            float nb1v[2];
            nb1v[0] = node_b1[L * HID + n0]; nb1v[1] = node_b1[L * HID + n1];
            f32x4 z0 = (f32x4){0.f,0.f,0.f,0.f}, z1 = z0;
            #pragma unroll
            for (int s = 0; s < 4; ++s) {
                short8 af = *(const short8*)(h_t + fo + s * 4 * TSTR);
                z0 = mfma16(af, *(const short8*)(n1t + (size_t)n0 * 2 * HID + 32 * s + 8 * kb), z0);
                z1 = mfma16(af, *(const short8*)(n1t + (size_t)n1 * 2 * HID + 32 * s + 8 * kb), z1);
            }
            #pragma unroll
            for (int s = 0; s < 4; ++s) {
                short8 af = *(const short8*)(ag_t + fo + s * 4 * TSTR);
                z0 = mfma16(af, *(const short8*)(n1t + (size_t)n0 * 2 * HID + HID + 32 * s + 8 * kb), z0);
                z1 = mfma16(af, *(const short8*)(n1t + (size_t)n1 * 2 * HID + HID + 32 * s + 8 * kb), z1);
            }
            #pragma unroll
            for (int reg = 0; reg < 4; ++reg) {
                int c = crow0 + reg;
                if (c < NPER) {
                    m0_t[tidx(c, n0)] = f2bf(silu_f(z0[reg] + nb1v[0]));
                    m0_t[tidx(c, n1)] = f2bf(silu_f(z1[reg] + nb1v[1]));
                }
            }
        }
        __syncthreads();

        // coord update + node MLP part 2: h += z @ nw2 + nb2
        if (tid < NPER * 3) coord_s[tid] += cacc_s[tid] * (1.0f / 51.0f);
        {
            float nb2v[2];
            nb2v[0] = node_b2[L * HID + n0]; nb2v[1] = node_b2[L * HID + n1];
            f32x4 d0 = (f32x4){0.f,0.f,0.f,0.f}, d1 = d0;
            #pragma unroll
            for (int s = 0; s < 4; ++s) {
                short8 af = *(const short8*)(m0_t + fo + s * 4 * TSTR);
                d0 = mfma16(af, *(const short8*)(n2t + (size_t)n0 * HID + 32 * s + 8 * kb), d0);
                d1 = mfma16(af, *(const short8*)(n2t + (size_t)n1 * HID + 32 * s + 8 * kb), d1);
            }
            #pragma unroll
            for (int reg = 0; reg < 4; ++reg) {
                int c = crow0 + reg;
                if (c < NPER) {
                    int i0 = tidx(c, n0), i1 = tidx(c, n1);
                    h_t[i0] = f2bf(bf2f(h_t[i0]) + d0[reg] + nb2v[0]);
                    h_t[i1] = f2bf(bf2f(h_t[i1]) + d1[reg] + nb2v[1]);
                }
            }
        }
        __syncthreads();
    }

    // ---------- head ----------
    float* gm = aggp;            // [128]
    float* eg = aggp + HID;      // [128]
    if (tid < HID) {
        float s = 0.f;
        for (int c = 0; c < NPER; ++c) s += bf2f(h_t[tidx(c, tid)]);
        gm[tid] = s * (1.0f / 52.0f);
    }
    __syncthreads();
    if (tid < HID) {
        float s = emb_out_b[tid];
        #pragma unroll 4
        for (int k = 0; k < HID; ++k) s += gm[k] * emb_out_w[k * HID + tid];
        eg[tid] = s;
    }
    __syncthreads();
    if (tid < 2 * LATD) {
        const int  l   = tid & (LATD - 1);
        const bool ism = tid < LATD;
        const float* W = ism ? mean_w : logvar_w;
        float s = ism ? mean_b[l] : logvar_b[l];
        #pragma unroll 4
        for (int k = 0; k < HID; ++k) s += eg[k] * W[k * LATD + l];
        out[(ism ? 0 : NGRAPH * LATD) + g * LATD + l] = s;
    }
}

extern "C" void kernel_launch(void* const* d_in, const int* in_sizes, int n_in,
                              void* d_out, int out_size, void* d_ws, size_t ws_size,
                              hipStream_t stream) {
    const float* x         = (const float*)d_in[0];
    const float* pos       = (const float*)d_in[1];
    // d_in[2..4] edge_row/edge_col/batch: block-diagonal FC structure is known.
    const float* emb_in_w  = (const float*)d_in[5];
    const float* emb_in_b  = (const float*)d_in[6];
    const float* edge_w1   = (const float*)d_in[7];
    const float* edge_b1   = (const float*)d_in[8];
    const float* edge_w2   = (const float*)d_in[9];
    const float* edge_b2   = (const float*)d_in[10];
    const float* node_w1   = (const float*)d_in[11];
    const float* node_b1   = (const float*)d_in[12];
    const float* node_w2   = (const float*)d_in[13];
    const float* node_b2   = (const float*)d_in[14];
    const float* coord_w1  = (const float*)d_in[15];
    const float* coord_b1  = (const float*)d_in[16];
    const float* coord_w2  = (const float*)d_in[17];
    const float* emb_out_w = (const float*)d_in[18];
    const float* emb_out_b = (const float*)d_in[19];
    const float* mean_w    = (const float*)d_in[20];
    const float* mean_b    = (const float*)d_in[21];
    const float* logvar_w  = (const float*)d_in[22];
    const float* logvar_b  = (const float*)d_in[23];

    unsigned short* ws = (unsigned short*)d_ws;   // needs 917,504 B

    conv_w<<<(WS_ELEMS + 255) / 256, 256, 0, stream>>>(edge_w1, edge_w2, coord_w1,
                                                       node_w1, node_w2, ws);

    (void)hipFuncSetAttribute(reinterpret_cast<const void*>(egnn_mfma),
                              hipFuncAttributeMaxDynamicSharedMemorySize,
                              (int)SHMEM_BYTES);

    hipLaunchKernelGGL(egnn_mfma, dim3(NGRAPH), dim3(TPB), SHMEM_BYTES, stream,
                       x, pos, emb_in_w, emb_in_b, edge_w1,
                       edge_b1, edge_b2, node_b1, node_b2,
                       coord_b1, coord_w2, emb_out_w, emb_out_b,
                       mean_w, mean_b, logvar_w, logvar_b,
                       ws, (float*)d_out);
}